// Round 12
// baseline (152.476 us; speedup 1.0000x reference)
//
#include <hip/hip_runtime.h>

// Problem constants (fixed by setup_inputs)
#define HW   256
#define Pp   33
#define PPAD 36        // padded patch row (ushort units)
#define OUTF 128
#define SIG  16

// conv1-output plane (bf16) for conv2 MFMA A-operands:
// [rowslot 6][parity 2][col' 16][kc 40] ushort.
#define KCP   40
#define PLROW (2 * 16 * KCP)
#define PLSZ  (6 * PLROW)        // 7680 shorts
#define IMS   40                 // im2col k-stride (shorts); 80B rows, b128-aligned

// ws layout (float offsets)
#define WS_W1FH 0       // [2 nt][64 lane][8 j] ushort = 512 f (conv1 A-frags hi)
#define WS_W1FL 512     // same, lo
#define WS_BHI  1024    // 18432 ushort = 9216 f (conv2 B-frags hi)
#define WS_BLO  10240   // conv2 B-frags lo
#define WS_WLT  19456   // [64][128] f32 = 8192

typedef __attribute__((ext_vector_type(8))) short v8s;    // 8 bf16
typedef __attribute__((ext_vector_type(4))) short v4s;    // 4 bf16 (b64)
typedef __attribute__((ext_vector_type(4))) float f32x4;  // MFMA acc

__device__ __forceinline__ unsigned short f2bf_rne(float x) {
  unsigned u = __float_as_uint(x);
  unsigned r = (u + 0x7FFFu + ((u >> 16) & 1u)) >> 16;
  return (unsigned short)r;
}
__device__ __forceinline__ float bf2f(unsigned short h) {
  return __uint_as_float(((unsigned)h) << 16);
}

__global__ __launch_bounds__(256) void prep_kernel(
    const float* __restrict__ w1, const float* __restrict__ w2,
    const float* __restrict__ wl, float* __restrict__ ws,
    float* __restrict__ out) {
  int t = blockIdx.x * 256 + threadIdx.x;
  int stride = gridDim.x * 256;
  if (blockIdx.x == 0 && threadIdx.x == 0) out[0] = 0.0f;
  // conv1 A-frags (A[m=ch][k]): k = 8*(l>>4)+j (27 padded to 32), ch = 16*nt+(l&15)
  unsigned short* w1h = (unsigned short*)(ws + WS_W1FH);
  unsigned short* w1lo = (unsigned short*)(ws + WS_W1FL);
  for (int i = t; i < 1024; i += stride) {
    int j  = i & 7;
    int l  = (i >> 3) & 63;
    int nt = i >> 9;
    int k  = 8 * (l >> 4) + j;
    int ch = 16 * nt + (l & 15);
    float v = (k < 27) ? w1[ch * 27 + k] : 0.0f;
    unsigned short h = f2bf_rne(v);
    w1h[i]  = h;
    w1lo[i] = f2bf_rne(v - bf2f(h));
  }
  // conv2 B-frags: n(ch)=w*16+(l&15), k(kc)=(l>>4)*8+j, per tap
  unsigned short* bhi = (unsigned short*)(ws + WS_BHI);
  unsigned short* blo = (unsigned short*)(ws + WS_BLO);
  for (int i = t; i < 18432; i += stride) {
    int j  = i & 7;
    int l  = (i >> 3) & 63;
    int w  = (i >> 9) & 3;
    int tp = i >> 11;
    int ch = w * 16 + (l & 15);
    int kc = ((l >> 4) << 3) + j;
    int ky = tp / 3, kx = tp - ky * 3;
    float v = w2[ch * 288 + kc * 9 + ky * 3 + kx];
    unsigned short h = f2bf_rne(v);
    bhi[i] = h;
    blo[i] = f2bf_rne(v - bf2f(h));
  }
  for (int i = t; i < 8192; i += stride) {
    int o = i & 127, ii = i >> 7;
    ws[WS_WLT + i] = wl[o * 64 + ii];
  }
}

// One block per (n,b); both sides in-block; one atomicAdd.
// R12 changes vs R11 (which was latency/barrier-bound: no pipe >35%, 98 barriers):
//  (a) conv1 MFMA operands SWAPPED: A=w1, B=im2col -> D[col=x][row=ch]; each
//      lane's 4 values are consecutive channels = contiguous in hiP -> ONE
//      ds_write_b64 instead of 4 ds_write_u16 (was the main conflict source).
//  (b) ONE barrier per y2: {conv1(rows 2y2+4,5; imcol pair bp) + build(rows
//      2y2+6,7 -> pair bp^1) + conv2(y2)} share a phase. hiP ring: conv1
//      writes slots (2y2+4,5)%6, conv2 reads (2y2..2y2+2)%6 - disjoint.
//      Barriers/side ~49 -> ~21. imcol doubled to 4 row-tiles (+5 KB LDS).
__global__ __launch_bounds__(256) void patch_cnn_kernel(
    const float* __restrict__ imgG, const float* __restrict__ imgS,
    const float* __restrict__ kpG,  const float* __restrict__ kpS,
    const float* __restrict__ b1g,  const float* __restrict__ b2g,
    const float* __restrict__ blg,  const float* __restrict__ ws,
    float* __restrict__ out) {
  __shared__ __align__(16) unsigned short patch[3 * Pp * PPAD];  // 7128 B
  __shared__ __align__(16) unsigned short imcol[4][32 * IMS];    // 10240 B
  __shared__ __align__(16) unsigned short hiP[PLSZ];             // 15360 B
  __shared__ float gapv[64];
  __shared__ float fstash[OUTF];
  __shared__ float lred[4];
  // total ~= 33.5 KB -> 4 blocks/CU by LDS

  const int bid  = blockIdx.x;          // grid 1024
  const int n    = bid >> 2;
  const int b    = bid & 3;
  const int tid  = threadIdx.x;
  const int wave = tid >> 6;
  const int lane = tid & 63;

  const int m16 = lane & 15;
  const int qq  = lane >> 4;
  const int mt  = wave & 1;             // conv1 x-tile
  const int nt  = wave >> 1;            // conv1 ch-tile

  // im2col build roles: thread = m(32) x k-quad(8)
  const int bm = tid & 31;
  const int kq = tid >> 5;
  int  boff[4];
  bool bval[4];
#pragma unroll
  for (int j = 0; j < 4; ++j) {
    int k = 4 * kq + j;
    bval[j] = (k < 27);
    int kk = bval[j] ? k : 0;
    int ci = kk / 9, r2 = kk - ci * 9, ky = r2 / 3, kx = r2 - ky * 3;
    boff[j] = (ci * Pp + ky) * PPAD + bm + kx;    // + r*PPAD at use
  }

  // conv1 A-frags (8 VGPRs each); bias float4 (ch = 16nt + 4qq + rg)
  const v8s w1hF = ((const v8s*)((const unsigned short*)(ws + WS_W1FH)))[nt * 64 + lane];
  const v8s w1lF = ((const v8s*)((const unsigned short*)(ws + WS_W1FL)))[nt * 64 + lane];
  const float4 b1q = *(const float4*)&b1g[16 * nt + 4 * qq];

  // conv2 frag pointers (global, L2-resident) and bias
  const v8s* bhW = (const v8s*)((const unsigned short*)(ws + WS_BHI)) + (wave * 64 + lane);
  const v8s* blW = (const v8s*)((const unsigned short*)(ws + WS_BLO)) + (wave * 64 + lane);
  const float b2v = b2g[wave * 16 + m16];

  auto build_row = [&](int r, int d) {
    unsigned short h[4];
#pragma unroll
    for (int j = 0; j < 4; ++j)
      h[j] = bval[j] ? patch[boff[j] + r * PPAD] : (unsigned short)0;
    unsigned w0 = (unsigned)h[0] | ((unsigned)h[1] << 16);
    unsigned w1_ = (unsigned)h[2] | ((unsigned)h[3] << 16);
    *(uint2*)&imcol[d][bm * IMS + 4 * kq] = make_uint2(w0, w1_);
  };

  // conv1 pair: rows r0,r0+1 from imcol pair bp (slots 2bp, 2bp+1)
  auto conv1_pair = [&](int bp, int r0) {
#pragma unroll
    for (int rr = 0; rr < 2; ++rr) {
      const int row = r0 + rr;
      if (row <= 30) {
        int sl = row % 6;
        v8s af = *(const v8s*)&imcol[2 * bp + rr][(16 * mt + m16) * IMS + 8 * qq];
        f32x4 a1 = {0.f, 0.f, 0.f, 0.f};
        a1 = __builtin_amdgcn_mfma_f32_16x16x32_bf16(w1hF, af, a1, 0, 0, 0);
        a1 = __builtin_amdgcn_mfma_f32_16x16x32_bf16(w1lF, af, a1, 0, 0, 0);
        const int x = 16 * mt + m16;      // D col = x; rows = ch 4qq..4qq+3
        v4s hv;
        hv[0] = (short)f2bf_rne(fmaxf(a1.x + b1q.x, 0.f));
        hv[1] = (short)f2bf_rne(fmaxf(a1.y + b1q.y, 0.f));
        hv[2] = (short)f2bf_rne(fmaxf(a1.z + b1q.z, 0.f));
        hv[3] = (short)f2bf_rne(fmaxf(a1.w + b1q.w, 0.f));
        const int idx = ((sl * 2 + (x & 1)) * 16 + (x >> 1)) * KCP + 16 * nt + 4 * qq;
        *(v4s*)&hiP[idx] = hv;            // one b64, 8B-aligned
      }
    }
  };

  float dd = 0.0f;

#pragma unroll 1
  for (int side = 0; side < 2; ++side) {
    const float* img = side ? imgS : imgG;
    const float* kp  = side ? kpS : kpG;

    int sx = (int)floorf(kp[n * 2 + 0] * 256.0f) - SIG;
    int sy = (int)floorf(kp[n * 2 + 1] * 256.0f) - SIG;
    sx = min(max(sx, 0), HW - Pp);
    sy = min(max(sy, 0), HW - Pp);

    // stage patch as bf16 pairs (coalesced float2 global reads)
    for (int i = tid; i < (3 * Pp * PPAD) / 2; i += 256) {
      int e  = 2 * i;
      int ci = e / (Pp * PPAD);
      int r2 = e - ci * (Pp * PPAD);
      int r  = r2 / PPAD;
      int cc = r2 - r * PPAD;
      float vx = 0.f, vy = 0.f;
      const float* rowp = &img[((b * 3 + ci) * HW + (sy + r)) * HW + sx];
      if (cc < 32) { float2 v = *(const float2*)(rowp + cc); vx = v.x; vy = v.y; }
      else if (cc == 32) { vx = rowp[32]; }
      unsigned pk = (unsigned)f2bf_rne(vx) | ((unsigned)f2bf_rne(vy) << 16);
      *(unsigned*)&patch[e] = pk;
    }
    __syncthreads();                       // patch ready

    // prologue: hiP rows 0..3, imcol pair0 = rows 4,5
    build_row(0, 0); build_row(1, 1);
    __syncthreads();
    conv1_pair(0, 0); build_row(2, 2); build_row(3, 3);
    __syncthreads();
    conv1_pair(1, 2); build_row(4, 0); build_row(5, 1);
    __syncthreads();

    float gapAcc = 0.0f;
    int s0 = 0;                            // (2*y2) % 6
    int bp = 0;
#pragma unroll 1
    for (int y2 = 0; y2 < 15; ++y2) {
      // conv1: rows 2y2+4,5 from pair bp
      const int r0 = 2 * y2 + 4;
      if (r0 <= 30) conv1_pair(bp, r0);
      // build: rows 2y2+6,7 into pair bp^1
      const int r1 = 2 * y2 + 6;
      if (r1 <= 30) {
        build_row(r1, 2 * (bp ^ 1));
        build_row(min(r1 + 1, 30), 2 * (bp ^ 1) + 1);
      }
      // conv2 y2: reads hiP rows 2y2..2y2+2 (slots disjoint from conv1 writes)
      f32x4 acc = {0.f, 0.f, 0.f, 0.f};
#pragma unroll
      for (int ky = 0; ky < 3; ++ky) {
        int sk = s0 + ky; if (sk >= 6) sk -= 6;
#pragma unroll
        for (int kx = 0; kx < 3; ++kx) {
          const int p = kx & 1;
          int cp = m16 + (kx >> 1); if (cp > 15) cp = 15;
          const int idx = ((sk * 2 + p) * 16 + cp) * KCP + qq * 8;
          v8s ah = *(const v8s*)&hiP[idx];
          const int tp = ky * 3 + kx;
          v8s bh = bhW[tp * 256];
          v8s bl = blW[tp * 256];
          acc = __builtin_amdgcn_mfma_f32_16x16x32_bf16(ah, bh, acc, 0, 0, 0);
          acc = __builtin_amdgcn_mfma_f32_16x16x32_bf16(ah, bl, acc, 0, 0, 0);
        }
      }
      {
        float s = fmaxf(acc.x + b2v, 0.f) + fmaxf(acc.y + b2v, 0.f) +
                  fmaxf(acc.z + b2v, 0.f);
        if (qq < 3) s += fmaxf(acc.w + b2v, 0.f);   // xout=15 is pad
        gapAcc += s;
      }
      __syncthreads();                     // the single per-y2 barrier
      s0 += 2; if (s0 >= 6) s0 -= 6;
      bp ^= 1;
    }

    // reduce gapAcc over kc-quads
    gapAcc += __shfl_down(gapAcc, 32, 64);
    gapAcc += __shfl_down(gapAcc, 16, 64);
    if (lane < 16) gapv[wave * 16 + m16] = gapAcc * (1.0f / 225.0f);
    __syncthreads();

    if (tid < OUTF) {
      float f = blg[tid];
#pragma unroll 8
      for (int i = 0; i < 64; ++i) f = fmaf(gapv[i], ws[WS_WLT + i * OUTF + tid], f);
      if (side == 0) fstash[tid] = f;
      else { float d = f - fstash[tid]; dd = d * d; }
    }
    __syncthreads();
  }

  // block reduction -> one atomicAdd
  dd += __shfl_down(dd, 32, 64);
  dd += __shfl_down(dd, 16, 64);
  dd += __shfl_down(dd, 8, 64);
  dd += __shfl_down(dd, 4, 64);
  dd += __shfl_down(dd, 2, 64);
  dd += __shfl_down(dd, 1, 64);
  if (lane == 0) lred[wave] = dd;
  __syncthreads();
  if (tid == 0) {
    float s = (lred[0] + lred[1]) + (lred[2] + lred[3]);
    atomicAdd(out, s * (1.0f / 131072.0f));
  }
}

extern "C" void kernel_launch(void* const* d_in, const int* in_sizes, int n_in,
                              void* d_out, int out_size, void* d_ws, size_t ws_size,
                              hipStream_t stream) {
  const float* imgG = (const float*)d_in[0];
  const float* imgS = (const float*)d_in[1];
  const float* kpG  = (const float*)d_in[2];
  const float* kpS  = (const float*)d_in[3];
  const float* w1   = (const float*)d_in[4];
  const float* b1   = (const float*)d_in[5];
  const float* w2   = (const float*)d_in[6];
  const float* b2   = (const float*)d_in[7];
  const float* wl   = (const float*)d_in[8];
  const float* bl   = (const float*)d_in[9];
  float* ws  = (float*)d_ws;
  float* out = (float*)d_out;

  hipLaunchKernelGGL(prep_kernel, dim3(32), dim3(256), 0, stream, w1, w2, wl, ws, out);
  hipLaunchKernelGGL(patch_cnn_kernel, dim3(1024), dim3(256), 0, stream,
                     imgG, imgS, kpG, kpS, b1, b2, bl, ws, out);
}